// Round 1
// baseline (158.755 us; speedup 1.0000x reference)
//
#include <hip/hip_runtime.h>
#include <hip/hip_bf16.h>

// Problem constants
#define BATCH 32
#define LTOT 4096
#define CCH 64
#define NFFT 16
#define HOP 4
#define NF 9            // n_fft/2+1
#define T_FR 1025       // 1 + L/HOP
#define T_ROWS 1032     // padded rows in mag workspace (rows >= 1025 zeroed)
#define ICH 576         // C * NF
#define OCH 512
#define TY 1023         // conv output length
#define OUTW 128

typedef __attribute__((ext_vector_type(8))) _Float16 half8;
typedef __attribute__((ext_vector_type(4))) float floatx4;

// cos/sin(n*pi/8) for n = 0..15 — compile-time twiddles.
__device__ constexpr float C16[16] = {
    1.0f,  0.923879533f,  0.707106781f,  0.382683432f,  0.0f, -0.382683432f,
   -0.707106781f, -0.923879533f, -1.0f, -0.923879533f, -0.707106781f,
   -0.382683432f,  0.0f,  0.382683432f,  0.707106781f,  0.923879533f};
__device__ constexpr float S16[16] = {
    0.0f,  0.382683432f,  0.707106781f,  0.923879533f,  1.0f,  0.923879533f,
    0.707106781f,  0.382683432f,  0.0f, -0.382683432f, -0.707106781f,
   -0.923879533f, -1.0f, -0.923879533f, -0.707106781f, -0.382683432f};

// R16 conv geometry: 256(o) x 256(t) block, 512 threads (8 waves, 2x4),
// BK=64, double-buffered A(per-tap) and B(per-ib) LDS, 1 barrier / step.
#define BK 64

__device__ __forceinline__ void async_copy16(const _Float16* g, _Float16* l) {
  __builtin_amdgcn_global_load_lds(
      (const __attribute__((address_space(1))) unsigned int*)g,
      (__attribute__((address_space(3))) unsigned int*)l, 16, 0, 0);
}

// ---------------------------------------------------------------------------
// Kernel 1: STFT magnitude + weight repack (merged).  (unchanged, ~13 us)
// x [B,L,C] fp32 -> m_ws [b][t][f*64+c] fp16 (f-major i-permutation, shared
// with the weight repack so the conv reduction is a pure GEMM over i).
// ---------------------------------------------------------------------------
__global__ __launch_bounds__(256) void stft_wrepack_kernel(
    const float* __restrict__ x, const float* __restrict__ weight,
    _Float16* __restrict__ m_ws, _Float16* __restrict__ wk) {
  const int b = blockIdx.y;
  const int t0 = blockIdx.x * 4;
  const int tid = threadIdx.x;

  // ---- weight repack slice (independent of stft work) ----
  const int gid = (b * 258 + blockIdx.x) * 256 + tid;
  if (gid < OCH * ICH) {
    int o = gid / ICH, i = gid - o * ICH;
    int c = i / 9, f = i - c * 9;
    const float* src = weight + (size_t)o * (ICH * 3) + i * 3;
    const size_t dst = (size_t)o * ICH + f * 64 + c;
#pragma unroll
    for (int k = 0; k < 3; ++k)
      wk[(size_t)k * OCH * ICH + dst] = (_Float16)src[k];
  }

  // ---- stft tile ----
  __shared__ float xs[28 * 64];   // frames for 4 t: 4*4+12 = 28 rows of x
  const int l0 = t0 * HOP - 8;
  const float* xb = x + (size_t)b * LTOT * CCH;
#pragma unroll
  for (int it = 0; it < 7; ++it) {
    int e = it * 256 + tid;
    int r = e >> 6, c = e & 63;
    int l = l0 + r;
    if (l < 0) l = -l;
    if (l >= LTOT) l = 2 * LTOT - 2 - l;
    xs[r * 64 + c] = xb[(size_t)l * CCH + c];
  }
  __syncthreads();

  const int c = tid & 63, tq = tid >> 6;
  const int t = t0 + tq;    // t <= 1031 < T_ROWS
  _Float16* o_ptr = m_ws + ((size_t)b * T_ROWS + t) * ICH + c;
  if (t >= T_FR) {
#pragma unroll
    for (int f = 0; f < NF; ++f) o_ptr[f * 64] = (_Float16)0.0f;
    return;
  }
  float wx[16];
#pragma unroll
  for (int j = 0; j < 16; ++j)
    wx[j] = xs[(tq * 4 + j) * 64 + c] * (0.5f * (1.0f - C16[j]));
  float s[8], d[8];
#pragma unroll
  for (int j = 1; j < 8; ++j) {
    s[j] = wx[j] + wx[16 - j];
    d[j] = wx[j] - wx[16 - j];
  }
#pragma unroll
  for (int f = 0; f < NF; ++f) {
    float re = wx[0] + ((f & 1) ? -wx[8] : wx[8]);
    float im = 0.0f;
#pragma unroll
    for (int j = 1; j < 8; ++j) {
      re += s[j] * C16[(f * j) & 15];
      im += d[j] * S16[(f * j) & 15];
    }
    o_ptr[f * 64] = (_Float16)sqrtf(re * re + im * im);
  }
}

// ---------------------------------------------------------------------------
// Kernel 2 (R16 rewrite): conv-as-GEMM, 256(o) x 256(t) tile, 512 threads.
//   y[b][t][o] = sum_k sum_i wk[k][o][i] * m[b][t+k][i]
// Old structure (R13/R15): 128x256, 2 barriers per (ib,tap) = 54 barrier
// pairs; rocprof showed per-ib time == MFMA + LDS-read + staging SERIALIZED
// (MfmaUtil 40%).  New structure: double-buffered A (per-tap 32 KB) and B
// (per-ib 33 KB) LDS = 128.5 KiB, ONE barrier per (ib,tap) step (27 total).
// Each step issues the next step's A stage (and next ib's B stage on tap 0,
// 3 steps = ~7.5k cyc of lead) BEFORE its 64 MFMA/wave — the compiler's
// vmcnt(0)-before-barrier then drains already-complete loads, and ds_read
// interleaves with MFMA inside the long barrier-free phase.
// Proven fragment swizzle kept verbatim: global source pre-swizzled
// (srow*ICH + (l7^srow)*8), LDS linear, XOR on the ds_read column.
// XCD remap: the 2 o-tile blocks sharing one B panel (same b,t0) get linear
// IDs differing by 8 -> same lid%8 -> same XCD L2 (R15 geometry, 2-member
// groups).  grid = 256 blocks = 1 block/CU, 8 waves (2 waves/SIMD).
// NOTE (R5): no per-element atomics in epilogue (2.3x regression).
// NOTE (R9): no cooperative grid.sync fusion (3.7x regression).
// NOTE (R10): A must go through LDS via async DMA — direct L2 reads thrash
// the 4 MB XCD L2.
// ---------------------------------------------------------------------------
__global__ __launch_bounds__(512, 2) void conv_gemm_kernel(
    const _Float16* __restrict__ m_ws, const _Float16* __restrict__ wk,
    _Float16* __restrict__ y) {
  // XCD-aware remap of linear ID -> (o-tile, t-tile, batch)
  const int lid = blockIdx.x;            // 0..255
  const int xcd = lid & 7;
  const int rest = lid >> 3;             // 0..31
  const int m = rest & 1;                // o-tile member 0..1
  const int gg = rest >> 1;              // 0..15
  const int g = xcd + 8 * gg;            // B-panel group 0..127 = (t,b)
  const int b = g >> 2;
  const int o0 = m * 256;
  const int t0 = (g & 3) * 256;

  const int tid = threadIdx.x;
  const int wave = tid >> 6, lane = tid & 63;
  const int wm = wave >> 2, wn = wave & 3;     // 2(o) x 4(t) wave grid

  __shared__ _Float16 as[2][256 * 64];    // 2 x 32 KB   (A: weights, one tap)
  __shared__ _Float16 bs[2][258 * 64];    // 2 x 32.25 KB (B: mag rows +2 pad)

  floatx4 acc[8][4];
#pragma unroll
  for (int mt = 0; mt < 8; ++mt)
#pragma unroll
    for (int nt = 0; nt < 4; ++nt)
      acc[mt][nt] = (floatx4)0.0f;

  const _Float16* mb = m_ws + (size_t)b * T_ROWS * ICH;
  const int frow = lane & 15;
  const int quad = lane >> 4;
  const int l7 = lane & 7;
  const int srow = lane >> 3;
  const int ssrc_off = srow * ICH + (l7 ^ srow) * 8;

  // ---- prologue: stage A(ib=0,tap=0) -> as[0], B(ib=0) -> bs[0] ----
  {
    const _Float16* ag = wk + (size_t)o0 * ICH;          // tap 0, i0 = 0
#pragma unroll
    for (int it = 0; it < 4; ++it) {
      const int seg = wave * 4 + it;                     // 32 segs x 8 rows
      async_copy16(ag + (size_t)(seg * 8) * ICH + ssrc_off, &as[0][seg * 512]);
    }
    const _Float16* bg = mb + (size_t)t0 * ICH;          // i0 = 0
#pragma unroll
    for (int it = 0; it < 4; ++it) {
      const int seg = wave * 4 + it;
      async_copy16(bg + (size_t)(seg * 8) * ICH + ssrc_off, &bs[0][seg * 512]);
    }
    if (tid < 16)   // rows 256,257 (t0 max 768 -> row 1025 < T_ROWS, zeroed)
      async_copy16(bg + (size_t)256 * ICH + ssrc_off, &bs[0][256 * 64]);
  }
  __syncthreads();

  int abuf = 0;
  for (int ib = 0; ib < 9; ++ib) {
#pragma unroll
    for (int ksh = 0; ksh < 3; ++ksh) {
      // ---- issue next-step A stage (into the other A buffer) ----
      if (ib < 8 || ksh < 2) {
        const int nib = (ksh == 2) ? ib + 1 : ib;
        const int nksh = (ksh == 2) ? 0 : ksh + 1;
        const _Float16* ag =
            wk + ((size_t)nksh * OCH + o0) * ICH + nib * 64;
#pragma unroll
        for (int it = 0; it < 4; ++it) {
          const int seg = wave * 4 + it;
          async_copy16(ag + (size_t)(seg * 8) * ICH + ssrc_off,
                       &as[abuf ^ 1][seg * 512]);
        }
      }
      // ---- on tap 0: issue next-ib B stage (needed 3 steps later) ----
      if (ksh == 0 && ib < 8) {
        const _Float16* bg = mb + (size_t)t0 * ICH + (ib + 1) * 64;
#pragma unroll
        for (int it = 0; it < 4; ++it) {
          const int seg = wave * 4 + it;
          async_copy16(bg + (size_t)(seg * 8) * ICH + ssrc_off,
                       &bs[(ib + 1) & 1][seg * 512]);
        }
        if (tid < 16)
          async_copy16(bg + (size_t)256 * ICH + ssrc_off,
                       &bs[(ib + 1) & 1][256 * 64]);
      }

      // ---- compute: 64 MFMA/wave from as[abuf], bs[ib&1] ----
      const int rb7 = (frow + ksh) & 7;
      const _Float16* asb = as[abuf];
      const _Float16* bsb = bs[ib & 1];
#pragma unroll
      for (int kk2 = 0; kk2 < 2; ++kk2) {
        const int jj = kk2 * 4 + quad;
        const int coffA = ((jj ^ l7) << 3);
        const int coffB = ((jj ^ rb7) << 3);
        half8 af[8], bf[4];
#pragma unroll
        for (int mt = 0; mt < 8; ++mt)
          af[mt] =
              *(const half8*)(&asb[(wm * 128 + mt * 16 + frow) * 64 + coffA]);
#pragma unroll
        for (int nt = 0; nt < 4; ++nt)
          bf[nt] = *(const half8*)(
              &bsb[(wn * 64 + nt * 16 + frow + ksh) * 64 + coffB]);
        // first operand = t-fragment => D row (quad*4+reg) = t, D col = o
#pragma unroll
        for (int mt = 0; mt < 8; ++mt)
#pragma unroll
          for (int nt = 0; nt < 4; ++nt)
            acc[mt][nt] = __builtin_amdgcn_mfma_f32_16x16x32_f16(
                bf[nt], af[mt], acc[mt][nt], 0, 0, 0);
      }
      __syncthreads();   // vmcnt drain: staged loads already landed under MFMA
      abuf ^= 1;
    }
  }

  // epilogue: y[b][t][o] fp16, t padded to 1024 rows of OCH halves.
  // Loop order nt->r->mt: 8 mt-stores complete each contiguous 256 B segment
  // adjacently in program order -> L2 write-combine (R13 verified).
  const int col = lane & 15;
  _Float16* yb = y + (((size_t)b << 10)) * OCH;
#pragma unroll
  for (int nt = 0; nt < 4; ++nt) {
    const int tb = t0 + wn * 64 + nt * 16 + quad * 4;
#pragma unroll
    for (int r = 0; r < 4; ++r) {
      const int t = tb + r;
      if (t < TY) {
#pragma unroll
        for (int mt = 0; mt < 8; ++mt) {
          const int o = o0 + wm * 128 + mt * 16 + col;
          yb[(size_t)t * OCH + o] = (_Float16)acc[mt][nt][r];
        }
      }
    }
  }
}

// ---------------------------------------------------------------------------
// Kernel 3: adaptive avg pool (overlapping torch bins) + bias, half8 wide.
// out[b][w][o] = bias[o] + mean_{t in bin(w)} y[b][t][o]
// one (b, w, o-octet) per thread: 32*128*64 = 262144 = 1024 blocks x 256.
// ---------------------------------------------------------------------------
__global__ __launch_bounds__(256) void pool_kernel(const _Float16* __restrict__ y,
                                                   const float* __restrict__ bias,
                                                   float* __restrict__ out) {
  const int unit = blockIdx.x * 256 + threadIdx.x;
  const int b = unit >> 13;
  const int w = (unit >> 6) & 127;
  const int o = (unit & 63) * 8;
  const int start = (w * TY) >> 7;
  const int end = ((w + 1) * TY + 127) >> 7;
  const _Float16* yb = y + (((size_t)b << 10)) * OCH;
  float s[8];
#pragma unroll
  for (int i = 0; i < 8; ++i) s[i] = 0.0f;
  for (int t = start; t < end; ++t) {
    half8 v = *(const half8*)(yb + (size_t)t * OCH + o);
#pragma unroll
    for (int i = 0; i < 8; ++i) s[i] += (float)v[i];
  }
  const float inv = 1.0f / (float)(end - start);
  float* op = out + ((size_t)b * OUTW + w) * OCH + o;
  floatx4 r0, r1;
#pragma unroll
  for (int i = 0; i < 4; ++i) r0[i] = s[i] * inv + bias[o + i];
#pragma unroll
  for (int i = 0; i < 4; ++i) r1[i] = s[4 + i] * inv + bias[o + 4 + i];
  *(floatx4*)(op) = r0;
  *(floatx4*)(op + 4) = r1;
}

// ---------------------------------------------------------------------------
extern "C" void kernel_launch(void* const* d_in, const int* in_sizes, int n_in,
                              void* d_out, int out_size, void* d_ws, size_t ws_size,
                              hipStream_t stream) {
  const float* x = (const float*)d_in[0];       // [32, 4096, 64]
  const float* weight = (const float*)d_in[1];  // [512, 576, 3]
  const float* bias = (const float*)d_in[2];    // [512]
  float* out = (float*)d_out;                   // [32, 128, 512]

  char* ws = (char*)d_ws;
  const size_t m_bytes = (size_t)BATCH * T_ROWS * ICH * sizeof(_Float16);  // 38,043,648
  const size_t w_bytes = (size_t)3 * OCH * ICH * sizeof(_Float16);         // 1,769,472
  _Float16* m_ws = (_Float16*)ws;
  _Float16* wk = (_Float16*)(ws + m_bytes);
  _Float16* y = (_Float16*)(ws + m_bytes + w_bytes);  // [32][1024][512] fp16

  hipLaunchKernelGGL(stft_wrepack_kernel, dim3(258, BATCH), dim3(256), 0,
                     stream, x, weight, m_ws, wk);
  hipLaunchKernelGGL(conv_gemm_kernel, dim3(256), dim3(512), 0, stream,
                     m_ws, wk, y);
  hipLaunchKernelGGL(pool_kernel, dim3(OUTW * BATCH / 4), dim3(256), 0, stream,
                     y, bias, out);
}

// Round 2
// 157.634 us; speedup vs baseline: 1.0071x; 1.0071x over previous
//
#include <hip/hip_runtime.h>
#include <hip/hip_bf16.h>

// Problem constants
#define BATCH 32
#define LTOT 4096
#define CCH 64
#define NFFT 16
#define HOP 4
#define NF 9            // n_fft/2+1
#define T_FR 1025       // 1 + L/HOP
#define T_ROWS 1032     // padded rows in mag workspace (rows >= 1025 zeroed)
#define ICH 576         // C * NF
#define OCH 512
#define TY 1023         // conv output length
#define OUTW 128

typedef __attribute__((ext_vector_type(8))) _Float16 half8;
typedef __attribute__((ext_vector_type(4))) float floatx4;

// cos/sin(n*pi/8) for n = 0..15 — compile-time twiddles.
__device__ constexpr float C16[16] = {
    1.0f,  0.923879533f,  0.707106781f,  0.382683432f,  0.0f, -0.382683432f,
   -0.707106781f, -0.923879533f, -1.0f, -0.923879533f, -0.707106781f,
   -0.382683432f,  0.0f,  0.382683432f,  0.707106781f,  0.923879533f};
__device__ constexpr float S16[16] = {
    0.0f,  0.382683432f,  0.707106781f,  0.923879533f,  1.0f,  0.923879533f,
    0.707106781f,  0.382683432f,  0.0f, -0.382683432f, -0.707106781f,
   -0.923879533f, -1.0f, -0.923879533f, -0.707106781f, -0.382683432f};

__device__ __forceinline__ void async_copy16(const _Float16* g, _Float16* l) {
  __builtin_amdgcn_global_load_lds(
      (const __attribute__((address_space(1))) unsigned int*)g,
      (__attribute__((address_space(3))) unsigned int*)l, 16, 0, 0);
}

// raw barrier + counted vmcnt (asm so no compiler-inserted vmcnt(0) drain)
#define SBAR() asm volatile("s_barrier" ::: "memory")
#define WAITV(N) asm volatile("s_waitcnt vmcnt(" #N ")" ::: "memory")

// ---------------------------------------------------------------------------
// Kernel 1: STFT magnitude + weight repack (merged).  (unchanged, ~13 us)
// x [B,L,C] fp32 -> m_ws [b][t][f*64+c] fp16 (f-major i-permutation, shared
// with the weight repack so the conv reduction is a pure GEMM over i).
// ---------------------------------------------------------------------------
__global__ __launch_bounds__(256) void stft_wrepack_kernel(
    const float* __restrict__ x, const float* __restrict__ weight,
    _Float16* __restrict__ m_ws, _Float16* __restrict__ wk) {
  const int b = blockIdx.y;
  const int t0 = blockIdx.x * 4;
  const int tid = threadIdx.x;

  // ---- weight repack slice (independent of stft work) ----
  const int gid = (b * 258 + blockIdx.x) * 256 + tid;
  if (gid < OCH * ICH) {
    int o = gid / ICH, i = gid - o * ICH;
    int c = i / 9, f = i - c * 9;
    const float* src = weight + (size_t)o * (ICH * 3) + i * 3;
    const size_t dst = (size_t)o * ICH + f * 64 + c;
#pragma unroll
    for (int k = 0; k < 3; ++k)
      wk[(size_t)k * OCH * ICH + dst] = (_Float16)src[k];
  }

  // ---- stft tile ----
  __shared__ float xs[28 * 64];   // frames for 4 t: 4*4+12 = 28 rows of x
  const int l0 = t0 * HOP - 8;
  const float* xb = x + (size_t)b * LTOT * CCH;
#pragma unroll
  for (int it = 0; it < 7; ++it) {
    int e = it * 256 + tid;
    int r = e >> 6, c = e & 63;
    int l = l0 + r;
    if (l < 0) l = -l;
    if (l >= LTOT) l = 2 * LTOT - 2 - l;
    xs[r * 64 + c] = xb[(size_t)l * CCH + c];
  }
  __syncthreads();

  const int c = tid & 63, tq = tid >> 6;
  const int t = t0 + tq;    // t <= 1031 < T_ROWS
  _Float16* o_ptr = m_ws + ((size_t)b * T_ROWS + t) * ICH + c;
  if (t >= T_FR) {
#pragma unroll
    for (int f = 0; f < NF; ++f) o_ptr[f * 64] = (_Float16)0.0f;
    return;
  }
  float wx[16];
#pragma unroll
  for (int j = 0; j < 16; ++j)
    wx[j] = xs[(tq * 4 + j) * 64 + c] * (0.5f * (1.0f - C16[j]));
  float s[8], d[8];
#pragma unroll
  for (int j = 1; j < 8; ++j) {
    s[j] = wx[j] + wx[16 - j];
    d[j] = wx[j] - wx[16 - j];
  }
#pragma unroll
  for (int f = 0; f < NF; ++f) {
    float re = wx[0] + ((f & 1) ? -wx[8] : wx[8]);
    float im = 0.0f;
#pragma unroll
    for (int j = 1; j < 8; ++j) {
      re += s[j] * C16[(f * j) & 15];
      im += d[j] * S16[(f * j) & 15];
    }
    o_ptr[f * 64] = (_Float16)sqrtf(re * re + im * im);
  }
}

// ---------------------------------------------------------------------------
// Kernel 2 (R17): conv-as-GEMM, 256(o) x 256(t) tile, 512 threads, with the
// counted-vmcnt / raw-barrier pipeline (T3+T4) + setprio (T5).
//   y[b][t][o] = sum_k sum_i wk[k][o][i] * m[b][t+k][i]
// R16 post-mortem: __syncthreads' implicit vmcnt(0) drained the same-step
// prefetch, and 1 block/CU barrier lockstep made the LDS-read pipe (~2.3k
// cyc/step) and matrix pipe (~2.5k cyc/step) ALTERNATE -> 5.6k cyc/step.
// R17 per (ib,tap) step:
//   issue A-prefetch(step+1) [4/wave] (+B-prefetch(ib+1) [5/wave] on tap 0)
//   s_waitcnt vmcnt(K)  K=9 taps 0/1, K=4 tap 2  (prev-step loads confirmed,
//                        this-step loads stay in flight ACROSS the barrier)
//   s_barrier            (raw: no drain)
//   ds_read kk2=0 frags; s_barrier (m201 stagger: laggards' MFMA overlaps
//   others' in-flight reads); setprio1 32 MFMA setprio0;
//   ds_read kk2=1 frags; setprio1 32 MFMA setprio0; s_barrier (reads done
//   before next step's DMA overwrites the buffer just read)
// Per-wave vmcnt counts are UNIFORM: B tile padded to 264 rows; the 2-row
// overhang became a whole-wave shared segment (all 8 waves DMA identical
// bytes to the same LDS region — benign).  B lead = 2 steps (>= HBM 900cy),
// A lead = 1 step (L2-resident weights).
// Proven fragment swizzle kept verbatim (pre-swizzled global source, linear
// LDS, XOR on read column; measured 0 bank conflicts).
// XCD remap: 2 o-tile blocks sharing one B panel differ by 8 in linear ID
// -> same XCD L2.  grid = 256 = 1 block/CU, 8 waves (2/SIMD).
// NOTE (R5): no per-element atomics in epilogue (2.3x regression).
// NOTE (R9): no cooperative grid.sync fusion (3.7x regression).
// NOTE (R10): A must go through LDS via async DMA — direct L2 reads thrash
// the 4 MB XCD L2.
// ---------------------------------------------------------------------------
__global__ __launch_bounds__(512, 2) void conv_gemm_kernel(
    const _Float16* __restrict__ m_ws, const _Float16* __restrict__ wk,
    _Float16* __restrict__ y) {
  // XCD-aware remap of linear ID -> (o-tile, t-tile, batch)
  const int lid = blockIdx.x;            // 0..255
  const int xcd = lid & 7;
  const int rest = lid >> 3;             // 0..31
  const int m = rest & 1;                // o-tile member 0..1
  const int gg = rest >> 1;              // 0..15
  const int g = xcd + 8 * gg;            // B-panel group 0..127 = (t,b)
  const int b = g >> 2;
  const int o0 = m * 256;
  const int t0 = (g & 3) * 256;

  const int tid = threadIdx.x;
  const int wave = tid >> 6, lane = tid & 63;
  const int wm = wave >> 2, wn = wave & 3;     // 2(o) x 4(t) wave grid

  __shared__ _Float16 as[2][256 * 64];    // 2 x 32 KB     (A: weights, one tap)
  __shared__ _Float16 bs[2][264 * 64];    // 2 x 33 KB     (B: mag rows, 264-pad)

  floatx4 acc[8][4];
#pragma unroll
  for (int mt = 0; mt < 8; ++mt)
#pragma unroll
    for (int nt = 0; nt < 4; ++nt)
      acc[mt][nt] = (floatx4)0.0f;

  const _Float16* mb = m_ws + (size_t)b * T_ROWS * ICH;
  const int frow = lane & 15;
  const int quad = lane >> 4;
  const int l7 = lane & 7;
  const int srow = lane >> 3;
  const int ssrc_off = srow * ICH + (l7 ^ srow) * 8;

  // ---- staging helpers: per-wave vmem counts are UNIFORM (A=4, B=5) ----
#define STAGE_A(tap, ibx, buf)                                               \
  {                                                                          \
    const _Float16* ag = wk + ((size_t)(tap) * OCH + o0) * ICH + (ibx) * 64; \
    _Float16* dst = &as[buf][0];                                             \
    _Pragma("unroll") for (int it = 0; it < 4; ++it) {                       \
      const int seg = wave * 4 + it;                                         \
      async_copy16(ag + (size_t)(seg * 8) * ICH + ssrc_off, dst + seg * 512);\
    }                                                                        \
  }
#define STAGE_B(ibx, buf)                                                    \
  {                                                                          \
    const _Float16* bg = mb + (size_t)t0 * ICH + (ibx) * 64;                 \
    _Float16* dst = &bs[buf][0];                                             \
    _Pragma("unroll") for (int it = 0; it < 4; ++it) {                       \
      const int seg = wave * 4 + it;                                         \
      async_copy16(bg + (size_t)(seg * 8) * ICH + ssrc_off, dst + seg * 512);\
    }                                                                        \
    /* rows 256..263: whole-wave shared segment, all waves write same data */\
    async_copy16(bg + (size_t)256 * ICH + ssrc_off, dst + 256 * 64);         \
  }

  // ---- prologue: A(0,0) -> as[0], B(0) -> bs[0] (confirmed at step (0,0))
  STAGE_A(0, 0, 0);
  STAGE_B(0, 0);
  asm volatile("" ::: "memory");   // pin prologue issue order vs loop issues

  int abuf = 0;
  for (int ib = 0; ib < 9; ++ib) {
    const _Float16* bsb = bs[ib & 1];
#pragma unroll
    for (int ksh = 0; ksh < 3; ++ksh) {
      // ---- issue next-step A prefetch (distance 1) ----
      if (ib < 8 || ksh < 2) {
        const int nib = (ksh == 2) ? ib + 1 : ib;
        const int nksh = (ksh == 2) ? 0 : ksh + 1;
        STAGE_A(nksh, nib, abuf ^ 1);
      }
      // ---- tap 0: issue next-ib B prefetch (distance = 2 steps of flight)
      if (ksh == 0 && ib < 8) STAGE_B(ib + 1, (ib + 1) & 1);

      // ---- counted wait: confirm THIS step's buffers, leave new loads in
      //      flight.  FIFO per wave: taps 0/1 leave {B_next(5), A_next(4)}
      //      -> vmcnt(9); tap 2 leaves {A_next(4)} -> vmcnt(4).
      if (ksh == 2) {
        if (ib < 8) { WAITV(4); } else { WAITV(0); }
      } else {
        if (ib < 8) { WAITV(9); } else { WAITV(4); }
      }
      SBAR();   // all waves confirmed: as[abuf], bs[ib&1] valid

      const int rb7 = (frow + ksh) & 7;
      const _Float16* asb = as[abuf];

      // ---- kk2 = 0: reads, stagger-barrier, MFMA ----
      half8 af[8], bf[4];
      {
        const int coffA = ((quad ^ l7) << 3);
        const int coffB = ((quad ^ rb7) << 3);
#pragma unroll
        for (int mt = 0; mt < 8; ++mt)
          af[mt] =
              *(const half8*)(&asb[(wm * 128 + mt * 16 + frow) * 64 + coffA]);
#pragma unroll
        for (int nt = 0; nt < 4; ++nt)
          bf[nt] = *(const half8*)(
              &bsb[(wn * 64 + nt * 16 + frow + ksh) * 64 + coffB]);
      }
      SBAR();   // stagger point: these reads fly under laggard waves' MFMA
      __builtin_amdgcn_s_setprio(1);
#pragma unroll
      for (int mt = 0; mt < 8; ++mt)
#pragma unroll
        for (int nt = 0; nt < 4; ++nt)
          acc[mt][nt] = __builtin_amdgcn_mfma_f32_16x16x32_f16(
              bf[nt], af[mt], acc[mt][nt], 0, 0, 0);
      __builtin_amdgcn_s_setprio(0);

      // ---- kk2 = 1: reads (interleave with above via scheduler), MFMA ----
      half8 ag2[8], bg2[4];
      {
        const int jj = 4 + quad;
        const int coffA = ((jj ^ l7) << 3);
        const int coffB = ((jj ^ rb7) << 3);
#pragma unroll
        for (int mt = 0; mt < 8; ++mt)
          ag2[mt] =
              *(const half8*)(&asb[(wm * 128 + mt * 16 + frow) * 64 + coffA]);
#pragma unroll
        for (int nt = 0; nt < 4; ++nt)
          bg2[nt] = *(const half8*)(
              &bsb[(wn * 64 + nt * 16 + frow + ksh) * 64 + coffB]);
      }
      __builtin_amdgcn_s_setprio(1);
#pragma unroll
      for (int mt = 0; mt < 8; ++mt)
#pragma unroll
        for (int nt = 0; nt < 4; ++nt)
          acc[mt][nt] = __builtin_amdgcn_mfma_f32_16x16x32_f16(
              bg2[nt], ag2[mt], acc[mt][nt], 0, 0, 0);
      __builtin_amdgcn_s_setprio(0);

      SBAR();   // trailing: all reads of as[abuf]/bs done before next DMA
      abuf ^= 1;
    }
  }

  // epilogue: y[b][t][o] fp16, t padded to 1024 rows of OCH halves.
  // Loop order nt->r->mt: 8 mt-stores complete each contiguous 256 B segment
  // adjacently in program order -> L2 write-combine (R13 verified).
  const int col = lane & 15;
  _Float16* yb = y + (((size_t)b << 10)) * OCH;
#pragma unroll
  for (int nt = 0; nt < 4; ++nt) {
    const int tb = t0 + wn * 64 + nt * 16 + quad * 4;
#pragma unroll
    for (int r = 0; r < 4; ++r) {
      const int t = tb + r;
      if (t < TY) {
#pragma unroll
        for (int mt = 0; mt < 8; ++mt) {
          const int o = o0 + wm * 128 + mt * 16 + col;
          yb[(size_t)t * OCH + o] = (_Float16)acc[mt][nt][r];
        }
      }
    }
  }
}

// ---------------------------------------------------------------------------
// Kernel 3: adaptive avg pool (overlapping torch bins) + bias, half8 wide.
// out[b][w][o] = bias[o] + mean_{t in bin(w)} y[b][t][o]
// one (b, w, o-octet) per thread: 32*128*64 = 262144 = 1024 blocks x 256.
// ---------------------------------------------------------------------------
__global__ __launch_bounds__(256) void pool_kernel(const _Float16* __restrict__ y,
                                                   const float* __restrict__ bias,
                                                   float* __restrict__ out) {
  const int unit = blockIdx.x * 256 + threadIdx.x;
  const int b = unit >> 13;
  const int w = (unit >> 6) & 127;
  const int o = (unit & 63) * 8;
  const int start = (w * TY) >> 7;
  const int end = ((w + 1) * TY + 127) >> 7;
  const _Float16* yb = y + (((size_t)b << 10)) * OCH;
  float s[8];
#pragma unroll
  for (int i = 0; i < 8; ++i) s[i] = 0.0f;
  for (int t = start; t < end; ++t) {
    half8 v = *(const half8*)(yb + (size_t)t * OCH + o);
#pragma unroll
    for (int i = 0; i < 8; ++i) s[i] += (float)v[i];
  }
  const float inv = 1.0f / (float)(end - start);
  float* op = out + ((size_t)b * OUTW + w) * OCH + o;
  floatx4 r0, r1;
#pragma unroll
  for (int i = 0; i < 4; ++i) r0[i] = s[i] * inv + bias[o + i];
#pragma unroll
  for (int i = 0; i < 4; ++i) r1[i] = s[4 + i] * inv + bias[o + 4 + i];
  *(floatx4*)(op) = r0;
  *(floatx4*)(op + 4) = r1;
}

// ---------------------------------------------------------------------------
extern "C" void kernel_launch(void* const* d_in, const int* in_sizes, int n_in,
                              void* d_out, int out_size, void* d_ws, size_t ws_size,
                              hipStream_t stream) {
  const float* x = (const float*)d_in[0];       // [32, 4096, 64]
  const float* weight = (const float*)d_in[1];  // [512, 576, 3]
  const float* bias = (const float*)d_in[2];    // [512]
  float* out = (float*)d_out;                   // [32, 128, 512]

  char* ws = (char*)d_ws;
  const size_t m_bytes = (size_t)BATCH * T_ROWS * ICH * sizeof(_Float16);  // 38,043,648
  const size_t w_bytes = (size_t)3 * OCH * ICH * sizeof(_Float16);         // 1,769,472
  _Float16* m_ws = (_Float16*)ws;
  _Float16* wk = (_Float16*)(ws + m_bytes);
  _Float16* y = (_Float16*)(ws + m_bytes + w_bytes);  // [32][1024][512] fp16

  hipLaunchKernelGGL(stft_wrepack_kernel, dim3(258, BATCH), dim3(256), 0,
                     stream, x, weight, m_ws, wk);
  hipLaunchKernelGGL(conv_gemm_kernel, dim3(256), dim3(512), 0, stream,
                     m_ws, wk, y);
  hipLaunchKernelGGL(pool_kernel, dim3(OUTW * BATCH / 4), dim3(256), 0, stream,
                     y, bias, out);
}

// Round 3
// 150.402 us; speedup vs baseline: 1.0555x; 1.0481x over previous
//
#include <hip/hip_runtime.h>
#include <hip/hip_bf16.h>

// Problem constants
#define BATCH 32
#define LTOT 4096
#define CCH 64
#define NFFT 16
#define HOP 4
#define NF 9            // n_fft/2+1
#define T_FR 1025       // 1 + L/HOP
#define T_ROWS 1032     // padded rows in mag workspace (rows >= 1025 zeroed)
#define ICH 576         // C * NF
#define OCH 512
#define TY 1023         // conv output length
#define OUTW 128

typedef __attribute__((ext_vector_type(8))) _Float16 half8;
typedef __attribute__((ext_vector_type(4))) float floatx4;

// cos/sin(n*pi/8) for n = 0..15 — compile-time twiddles.
__device__ constexpr float C16[16] = {
    1.0f,  0.923879533f,  0.707106781f,  0.382683432f,  0.0f, -0.382683432f,
   -0.707106781f, -0.923879533f, -1.0f, -0.923879533f, -0.707106781f,
   -0.382683432f,  0.0f,  0.382683432f,  0.707106781f,  0.923879533f};
__device__ constexpr float S16[16] = {
    0.0f,  0.382683432f,  0.707106781f,  0.923879533f,  1.0f,  0.923879533f,
    0.707106781f,  0.382683432f,  0.0f, -0.382683432f, -0.707106781f,
   -0.923879533f, -1.0f, -0.923879533f, -0.707106781f, -0.382683432f};

__device__ __forceinline__ void async_copy16(const _Float16* g, _Float16* l) {
  __builtin_amdgcn_global_load_lds(
      (const __attribute__((address_space(1))) unsigned int*)g,
      (__attribute__((address_space(3))) unsigned int*)l, 16, 0, 0);
}

// ---------------------------------------------------------------------------
// Kernel 1: STFT magnitude + weight repack (merged).  (unchanged)
// x [B,L,C] fp32 -> m_ws [b][t][f*64+c] fp16 (f-major i-permutation, shared
// with the weight repack so the conv reduction is a pure GEMM over i).
// ---------------------------------------------------------------------------
__global__ __launch_bounds__(256) void stft_wrepack_kernel(
    const float* __restrict__ x, const float* __restrict__ weight,
    _Float16* __restrict__ m_ws, _Float16* __restrict__ wk) {
  const int b = blockIdx.y;
  const int t0 = blockIdx.x * 4;
  const int tid = threadIdx.x;

  // ---- weight repack slice (independent of stft work) ----
  const int gid = (b * 258 + blockIdx.x) * 256 + tid;
  if (gid < OCH * ICH) {
    int o = gid / ICH, i = gid - o * ICH;
    int c = i / 9, f = i - c * 9;
    const float* src = weight + (size_t)o * (ICH * 3) + i * 3;
    const size_t dst = (size_t)o * ICH + f * 64 + c;
#pragma unroll
    for (int k = 0; k < 3; ++k)
      wk[(size_t)k * OCH * ICH + dst] = (_Float16)src[k];
  }

  // ---- stft tile ----
  __shared__ float xs[28 * 64];   // frames for 4 t: 4*4+12 = 28 rows of x
  const int l0 = t0 * HOP - 8;
  const float* xb = x + (size_t)b * LTOT * CCH;
#pragma unroll
  for (int it = 0; it < 7; ++it) {
    int e = it * 256 + tid;
    int r = e >> 6, c = e & 63;
    int l = l0 + r;
    if (l < 0) l = -l;
    if (l >= LTOT) l = 2 * LTOT - 2 - l;
    xs[r * 64 + c] = xb[(size_t)l * CCH + c];
  }
  __syncthreads();

  const int c = tid & 63, tq = tid >> 6;
  const int t = t0 + tq;    // t <= 1031 < T_ROWS
  _Float16* o_ptr = m_ws + ((size_t)b * T_ROWS + t) * ICH + c;
  if (t >= T_FR) {
#pragma unroll
    for (int f = 0; f < NF; ++f) o_ptr[f * 64] = (_Float16)0.0f;
    return;
  }
  float wx[16];
#pragma unroll
  for (int j = 0; j < 16; ++j)
    wx[j] = xs[(tq * 4 + j) * 64 + c] * (0.5f * (1.0f - C16[j]));
  float s[8], d[8];
#pragma unroll
  for (int j = 1; j < 8; ++j) {
    s[j] = wx[j] + wx[16 - j];
    d[j] = wx[j] - wx[16 - j];
  }
#pragma unroll
  for (int f = 0; f < NF; ++f) {
    float re = wx[0] + ((f & 1) ? -wx[8] : wx[8]);
    float im = 0.0f;
#pragma unroll
    for (int j = 1; j < 8; ++j) {
      re += s[j] * C16[(f * j) & 15];
      im += d[j] * S16[(f * j) & 15];
    }
    o_ptr[f * 64] = (_Float16)sqrtf(re * re + im * im);
  }
}

// ---------------------------------------------------------------------------
// Kernel 2 (R18): conv-as-GEMM, 128(o) x 128(t) blocks, 128 threads, 4/CU.
//   y[b][t][o] = sum_k sum_i wk[k][o][i] * m[b][t+k][i]
// R16/R17 post-mortem: 1-block/CU schedules (syncthreads OR counted-vmcnt/
// raw-barrier/setprio) all land at 63-65 us — barrier lockstep alternates
// the LDS-read pipe (~2.3k cyc/step/CU) and matrix pipe (~2.5k cyc/step/CU)
// regardless of asm discipline.  The only measured win is TLP: R13's 2
// independent blocks/CU (56.5 us) de-phase naturally.  R18 extrapolates:
// 4 independent 128-thread blocks/CU (LDS 33 KB each), plain __syncthreads.
// One block's read-burst / stage-drain overlaps the other three's MFMA.
// Per-wave work per (ib,tap) step unchanged: 24 ds_read_b128, 64 MFMA.
// Proven fragment swizzle verbatim: pre-swizzled global source
// (srow*ICH + (l7^srow)*8), linear LDS, XOR on the read column (0 bank
// conflicts measured).
// XCD map: t-slice = lid&7 (one t-panel per XCD for all batches, B ~5 MB/XCD
// fetched once); the 4 o-member blocks of a panel are consecutive on the
// XCD -> B L2-hits.  grid = 1024 linear blocks = 4/CU exactly.
// NOTE (R5): no per-element atomics in epilogue (2.3x regression).
// NOTE (R9): no cooperative grid.sync fusion (3.7x regression).
// NOTE (R10): A must go through LDS via async DMA — direct L2 reads thrash
// the 4 MB XCD L2.
// NOTE (R16/R17): no 1-block/CU deep pipelines — lockstep serializes pipes.
// ---------------------------------------------------------------------------
__global__ __launch_bounds__(128, 2) void conv_gemm_kernel(
    const _Float16* __restrict__ m_ws, const _Float16* __restrict__ wk,
    _Float16* __restrict__ y) {
  // XCD-aware remap: lid = xcd + 8*(m4 + 4*pg)
  const int lid = blockIdx.x;            // 0..1023
  const int xcd = lid & 7;
  const int rest = lid >> 3;             // 0..127
  const int m4 = rest & 3;               // o-tile member 0..3
  const int b = rest >> 2;               // batch 0..31
  const int o0 = m4 * 128;
  const int t0 = xcd * 128;              // one t-slice per XCD

  const int tid = threadIdx.x;
  const int wave = tid >> 6, lane = tid & 63;

  __shared__ _Float16 as[128 * 64];      // 16 KB  (A: weights, one tap)
  __shared__ _Float16 bs[136 * 64];      // 17 KB  (B: mag rows t0..t0+135)

  floatx4 acc[4][8];
#pragma unroll
  for (int mt = 0; mt < 4; ++mt)
#pragma unroll
    for (int nt = 0; nt < 8; ++nt)
      acc[mt][nt] = (floatx4)0.0f;

  const _Float16* mb = m_ws + (size_t)b * T_ROWS * ICH;
  const int frow = lane & 15;
  const int quad = lane >> 4;
  const int l7 = lane & 7;
  const int srow = lane >> 3;
  const int ssrc_off = srow * ICH + (l7 ^ srow) * 8;

  for (int ib = 0; ib < 9; ++ib) {
    const int i0 = ib * 64;

    // ---- stage B rows t0 .. t0+135 (17 segments of 8 rows) ----
    {
      const _Float16* bg = mb + (size_t)t0 * ICH + i0;
#pragma unroll
      for (int it = 0; it < 8; ++it) {
        const int seg = wave * 8 + it;
        async_copy16(bg + (size_t)(seg * 8) * ICH + ssrc_off, &bs[seg * 512]);
      }
      // rows 128..135: both waves write identical data (benign duplicate)
      async_copy16(bg + (size_t)128 * ICH + ssrc_off, &bs[128 * 64]);
    }

#pragma unroll
    for (int ksh = 0; ksh < 3; ++ksh) {
      // ---- stage A (weights for tap ksh) ----
      const _Float16* ag = wk + ((size_t)ksh * OCH + o0) * ICH + i0;
#pragma unroll
      for (int it = 0; it < 8; ++it) {
        const int seg = wave * 8 + it;
        async_copy16(ag + (size_t)(seg * 8) * ICH + ssrc_off, &as[seg * 512]);
      }
      __syncthreads();   // drains vmcnt (B on tap 0 + A) + barrier

      const int rb7 = (frow + ksh) & 7;
#pragma unroll
      for (int kk2 = 0; kk2 < 2; ++kk2) {
        const int jj = kk2 * 4 + quad;
        const int coffA = ((jj ^ l7) << 3);
        const int coffB = ((jj ^ rb7) << 3);
        half8 af[4], bf[8];
#pragma unroll
        for (int mt = 0; mt < 4; ++mt)
          af[mt] =
              *(const half8*)(&as[(wave * 64 + mt * 16 + frow) * 64 + coffA]);
#pragma unroll
        for (int nt = 0; nt < 8; ++nt)
          bf[nt] = *(const half8*)(
              &bs[(nt * 16 + frow + ksh) * 64 + coffB]);
        // first operand = t-fragment => D row (quad*4+reg) = t, D col = o
#pragma unroll
        for (int mt = 0; mt < 4; ++mt)
#pragma unroll
          for (int nt = 0; nt < 8; ++nt)
            acc[mt][nt] = __builtin_amdgcn_mfma_f32_16x16x32_f16(
                bf[nt], af[mt], acc[mt][nt], 0, 0, 0);
      }
      __syncthreads();
    }
  }

  // epilogue: y[b][t][o] fp16, t padded to 1024 rows of OCH halves.
  // Loop order nt->r->mt: 4 mt-stores complete each contiguous 128 B segment
  // adjacently in program order -> L2 write-combine (R13 verified).
  const int col = lane & 15;
  _Float16* yb = y + (((size_t)b << 10)) * OCH;
#pragma unroll
  for (int nt = 0; nt < 8; ++nt) {
    const int tb = t0 + nt * 16 + quad * 4;
#pragma unroll
    for (int r = 0; r < 4; ++r) {
      const int t = tb + r;
      if (t < TY) {
#pragma unroll
        for (int mt = 0; mt < 4; ++mt) {
          const int o = o0 + wave * 64 + mt * 16 + col;
          yb[(size_t)t * OCH + o] = (_Float16)acc[mt][nt][r];
        }
      }
    }
  }
}

// ---------------------------------------------------------------------------
// Kernel 3: adaptive avg pool (overlapping torch bins) + bias, half8 wide.
// out[b][w][o] = bias[o] + mean_{t in bin(w)} y[b][t][o]
// one (b, w, o-octet) per thread: 32*128*64 = 262144 = 1024 blocks x 256.
// ---------------------------------------------------------------------------
__global__ __launch_bounds__(256) void pool_kernel(const _Float16* __restrict__ y,
                                                   const float* __restrict__ bias,
                                                   float* __restrict__ out) {
  const int unit = blockIdx.x * 256 + threadIdx.x;
  const int b = unit >> 13;
  const int w = (unit >> 6) & 127;
  const int o = (unit & 63) * 8;
  const int start = (w * TY) >> 7;
  const int end = ((w + 1) * TY + 127) >> 7;
  const _Float16* yb = y + (((size_t)b << 10)) * OCH;
  float s[8];
#pragma unroll
  for (int i = 0; i < 8; ++i) s[i] = 0.0f;
  for (int t = start; t < end; ++t) {
    half8 v = *(const half8*)(yb + (size_t)t * OCH + o);
#pragma unroll
    for (int i = 0; i < 8; ++i) s[i] += (float)v[i];
  }
  const float inv = 1.0f / (float)(end - start);
  float* op = out + ((size_t)b * OUTW + w) * OCH + o;
  floatx4 r0, r1;
#pragma unroll
  for (int i = 0; i < 4; ++i) r0[i] = s[i] * inv + bias[o + i];
#pragma unroll
  for (int i = 0; i < 4; ++i) r1[i] = s[4 + i] * inv + bias[o + 4 + i];
  *(floatx4*)(op) = r0;
  *(floatx4*)(op + 4) = r1;
}

// ---------------------------------------------------------------------------
extern "C" void kernel_launch(void* const* d_in, const int* in_sizes, int n_in,
                              void* d_out, int out_size, void* d_ws, size_t ws_size,
                              hipStream_t stream) {
  const float* x = (const float*)d_in[0];       // [32, 4096, 64]
  const float* weight = (const float*)d_in[1];  // [512, 576, 3]
  const float* bias = (const float*)d_in[2];    // [512]
  float* out = (float*)d_out;                   // [32, 128, 512]

  char* ws = (char*)d_ws;
  const size_t m_bytes = (size_t)BATCH * T_ROWS * ICH * sizeof(_Float16);  // 38,043,648
  const size_t w_bytes = (size_t)3 * OCH * ICH * sizeof(_Float16);         // 1,769,472
  _Float16* m_ws = (_Float16*)ws;
  _Float16* wk = (_Float16*)(ws + m_bytes);
  _Float16* y = (_Float16*)(ws + m_bytes + w_bytes);  // [32][1024][512] fp16

  hipLaunchKernelGGL(stft_wrepack_kernel, dim3(258, BATCH), dim3(256), 0,
                     stream, x, weight, m_ws, wk);
  hipLaunchKernelGGL(conv_gemm_kernel, dim3(1024), dim3(128), 0, stream,
                     m_ws, wk, y);
  hipLaunchKernelGGL(pool_kernel, dim3(OUTW * BATCH / 4), dim3(256), 0, stream,
                     y, bias, out);
}

// Round 5
// 149.501 us; speedup vs baseline: 1.0619x; 1.0060x over previous
//
#include <hip/hip_runtime.h>
#include <hip/hip_bf16.h>

// Problem constants
#define BATCH 32
#define LTOT 4096
#define CCH 64
#define NFFT 16
#define HOP 4
#define NF 9            // n_fft/2+1
#define T_FR 1025       // 1 + L/HOP
#define T_ROWS 1032     // padded rows in mag workspace (rows >= 1025 zeroed)
#define ICH 576         // C * NF
#define OCH 512
#define TY 1023         // conv output length
#define OUTW 128

typedef __attribute__((ext_vector_type(8))) _Float16 half8;
typedef __attribute__((ext_vector_type(4))) float floatx4;

// cos/sin(n*pi/8) for n = 0..15 — compile-time twiddles.
__device__ constexpr float C16[16] = {
    1.0f,  0.923879533f,  0.707106781f,  0.382683432f,  0.0f, -0.382683432f,
   -0.707106781f, -0.923879533f, -1.0f, -0.923879533f, -0.707106781f,
   -0.382683432f,  0.0f,  0.382683432f,  0.707106781f,  0.923879533f};
__device__ constexpr float S16[16] = {
    0.0f,  0.382683432f,  0.707106781f,  0.923879533f,  1.0f,  0.923879533f,
    0.707106781f,  0.382683432f,  0.0f, -0.382683432f, -0.707106781f,
   -0.923879533f, -1.0f, -0.923879533f, -0.707106781f, -0.382683432f};

#define BM 128
#define BN 256   // tile surface measured: BN=128 -> 57.6us, 192 -> 68.4us
                 // (FETCH 94MB: XCD scatter + over-read), 256 -> 55.3us. Keep 256.
#define BK 64

__device__ __forceinline__ void async_copy16(const _Float16* g, _Float16* l) {
  __builtin_amdgcn_global_load_lds(
      (const __attribute__((address_space(1))) unsigned int*)g,
      (__attribute__((address_space(3))) unsigned int*)l, 16, 0, 0);
}

// ---------------------------------------------------------------------------
// Kernel 1: STFT magnitude + weight repack (merged).
// x [B,L,C] fp32 -> m_ws [b][t][f*64+c] fp16 (f-major i-permutation, shared
// with the weight repack so the conv reduction is a pure GEMM over i).
// R19: x staging vectorized to float4 (16 B/lane, 448 loads/block vs 1792
// scalar — G13: hipcc does not auto-vectorize; 4B/lane was half-width).
// block = 256 = 64 c x 4 t; grid = (258 t-tiles, 32 b).
// ---------------------------------------------------------------------------
__global__ __launch_bounds__(256) void stft_wrepack_kernel(
    const float* __restrict__ x, const float* __restrict__ weight,
    _Float16* __restrict__ m_ws, _Float16* __restrict__ wk) {
  const int b = blockIdx.y;
  const int t0 = blockIdx.x * 4;
  const int tid = threadIdx.x;

  // ---- weight repack slice (independent of stft work) ----
  const int gid = (b * 258 + blockIdx.x) * 256 + tid;
  if (gid < OCH * ICH) {
    int o = gid / ICH, i = gid - o * ICH;
    int c = i / 9, f = i - c * 9;
    const float* src = weight + (size_t)o * (ICH * 3) + i * 3;
    const size_t dst = (size_t)o * ICH + f * 64 + c;
#pragma unroll
    for (int k = 0; k < 3; ++k)
      wk[(size_t)k * OCH * ICH + dst] = (_Float16)src[k];
  }

  // ---- stft tile ----
  __shared__ float xs[28 * 64];   // frames for 4 t: 4*4+12 = 28 rows of x
  const int l0 = t0 * HOP - 8;
  const float* xb = x + (size_t)b * LTOT * CCH;
  // float4 staging: 28 rows x 16 float4 cols = 448 units, 2 x 256 slots.
  // LDS write banks: lane's byte addr = r*256 + c4*16 -> 2-way (free, m136).
#pragma unroll
  for (int it = 0; it < 2; ++it) {
    int e = it * 256 + tid;
    int r = e >> 4, c4 = e & 15;
    if (r < 28) {
      int l = l0 + r;
      if (l < 0) l = -l;
      if (l >= LTOT) l = 2 * LTOT - 2 - l;
      *(floatx4*)(&xs[r * 64 + c4 * 4]) =
          *(const floatx4*)(&xb[(size_t)l * CCH + c4 * 4]);
    }
  }
  __syncthreads();

  const int c = tid & 63, tq = tid >> 6;
  const int t = t0 + tq;    // t <= 1031 < T_ROWS
  _Float16* o_ptr = m_ws + ((size_t)b * T_ROWS + t) * ICH + c;
  if (t >= T_FR) {
#pragma unroll
    for (int f = 0; f < NF; ++f) o_ptr[f * 64] = (_Float16)0.0f;
    return;
  }
  float wx[16];
#pragma unroll
  for (int j = 0; j < 16; ++j)
    wx[j] = xs[(tq * 4 + j) * 64 + c] * (0.5f * (1.0f - C16[j]));
  float s[8], d[8];
#pragma unroll
  for (int j = 1; j < 8; ++j) {
    s[j] = wx[j] + wx[16 - j];
    d[j] = wx[j] - wx[16 - j];
  }
#pragma unroll
  for (int f = 0; f < NF; ++f) {
    float re = wx[0] + ((f & 1) ? -wx[8] : wx[8]);
    float im = 0.0f;
#pragma unroll
    for (int j = 1; j < 8; ++j) {
      re += s[j] * C16[(f * j) & 15];
      im += d[j] * S16[(f * j) & 15];
    }
    o_ptr[f * 64] = (_Float16)sqrtf(re * re + im * im);
  }
}

// ---------------------------------------------------------------------------
// Kernel 2: conv-as-GEMM, 128(o) x 256(t) tile (R13 config, GEMM 55.3 us)
// + R15 XCD-aware work remap: the 4 o-tiles consuming one B-tile (same t,b)
// are assigned to linear block IDs {g%8 + 32*(g/8) + 8m}, all == g (mod 8),
// so under round-robin ID->XCD placement they share ONE XCD's L2 and B is
// fetched once per group (R14 showed placement geometry dominates FETCH:
// grid-x=6 scattered groups over 4 XCDs -> FETCH 94 MB, 68 us).
//   y[b][t][o] = sum_k sum_i wk[k][o][i] * m[b][t+k][i]
// Epilogue loop order nt->r->mt -> L2 write-combine (R13: WRITE 60->33 MB).
// NOTE (R5): no per-element atomics in epilogue (2.3x regression).
// NOTE (R9): no cooperative grid.sync fusion (3.7x regression).
// NOTE (R10): A must go through LDS via async DMA — direct L2 reads thrash
// the 4 MB XCD L2 (WRITE 45->112 MB, MfmaUtil 44->15%).
// NOTE (R16/R17/R18): structural arc CLOSED — dbuf 1-block/CU pipeline
// (63.2), counted-vmcnt/raw-barrier/setprio (64.5), 4x128-thread blocks
// (59.5) all lose to this config (56.5-56.7): per-CU matrix (~67k cyc),
// LDS-read (~61k cyc), VALU (~20k cyc) pipes serialize to their sum under
// every schedule tried; 2 independent 4-wave blocks/CU is the best measured
// de-phasing.  LDS-traffic/flop is fixed at (1/Wt+1/Wo)=3/128 for every
// register-viable wave tile, so no traffic lever remains either.
// grid = 512 linear blocks, block 256 (4 waves, 2(o) x 2(t-half)).
// ---------------------------------------------------------------------------
__global__ __launch_bounds__(256, 2) void conv_gemm_kernel(
    const _Float16* __restrict__ m_ws, const _Float16* __restrict__ wk,
    _Float16* __restrict__ y) {
  // XCD-aware remap of linear ID -> (t-tile, o-tile, batch)
  const int lid = blockIdx.x;            // 0..511
  const int xcd = lid & 7;
  const int rest = lid >> 3;             // 0..63
  const int m = rest & 3;                // o-tile member 0..3
  const int gg = rest >> 2;              // 0..15
  const int g = xcd + 8 * gg;            // B-tile group 0..127 = (t,b)
  const int b = g >> 2;
  const int o0 = m * BM;
  const int t0 = (g & 3) * BN;

  const int tid = threadIdx.x;
  const int wave = tid >> 6, lane = tid & 63;
  const int wm = wave >> 1, wn = wave & 1;     // 2x2 wave grid (o x t-half)

  __shared__ _Float16 as[BM * BK];        // 16 KB    (A: weights, tap-current)
  __shared__ _Float16 bs[(BN + 2) * BK];  // 32.25 KB (B: mag rows t0..t0+257)

  floatx4 acc[4][8];
#pragma unroll
  for (int mt = 0; mt < 4; ++mt)
#pragma unroll
    for (int nt = 0; nt < 8; ++nt)
      acc[mt][nt] = (floatx4)0.0f;

  const _Float16* mb = m_ws + (size_t)b * T_ROWS * ICH;
  const int frow = lane & 15;
  const int quad = lane >> 4;
  const int l7 = lane & 7;
  const int srow = lane >> 3;
  const int ssrc_off = srow * ICH + (l7 ^ srow) * 8;

  for (int ib = 0; ib < 9; ++ib) {
    const int i0 = ib * 64;
    const _Float16* bg = mb + (size_t)t0 * ICH + i0;

    // stage B rows t0 .. t0+257 (32 full 8-row segments + one 2-row partial)
#pragma unroll
    for (int it = 0; it < 8; ++it) {
      const int seg = wave * 8 + it;
      async_copy16(bg + (size_t)(seg * 8) * ICH + ssrc_off, &bs[seg * 512]);
    }
    if (tid < 16)   // rows 256,257 (t0 max 768 -> row 1025 < T_ROWS)
      async_copy16(bg + (size_t)256 * ICH + ssrc_off, &bs[256 * 64]);

#pragma unroll
    for (int ksh = 0; ksh < 3; ++ksh) {
      // stage A (weights for tap ksh)
      const _Float16* ag = wk + ((size_t)ksh * OCH + o0) * ICH + i0;
#pragma unroll
      for (int it = 0; it < 4; ++it) {
        const int seg = wave * 4 + it;
        async_copy16(ag + (size_t)(seg * 8) * ICH + ssrc_off, &as[seg * 512]);
      }
      __syncthreads();   // drains vmcnt (B once per ib + A) + barrier

      const int rb7 = (frow + ksh) & 7;
#pragma unroll
      for (int kk2 = 0; kk2 < 2; ++kk2) {
        const int jj = kk2 * 4 + quad;
        const int coffA = ((jj ^ l7) << 3);
        const int coffB = ((jj ^ rb7) << 3);
        half8 af[4], bf[8];
#pragma unroll
        for (int mt = 0; mt < 4; ++mt)
          af[mt] = *(const half8*)(&as[(wm * 64 + mt * 16 + frow) * 64 + coffA]);
#pragma unroll
        for (int nt = 0; nt < 8; ++nt)
          bf[nt] = *(const half8*)(
              &bs[(wn * 128 + nt * 16 + frow + ksh) * 64 + coffB]);
        // first operand = t-fragment => D row (quad*4+reg) = t, D col = o
#pragma unroll
        for (int mt = 0; mt < 4; ++mt)
#pragma unroll
          for (int nt = 0; nt < 8; ++nt)
            acc[mt][nt] = __builtin_amdgcn_mfma_f32_16x16x32_f16(
                bf[nt], af[mt], acc[mt][nt], 0, 0, 0);
      }
      __syncthreads();
    }
  }

  // epilogue: y[b][t][o] fp16, t padded to 1024 rows of OCH halves.
  // Loop order nt->r->mt: 4 mt-stores complete each contiguous 128 B segment
  // adjacently in program order -> L2 write-combine (R13 verified).
  const int col = lane & 15;
  _Float16* yb = y + (((size_t)b << 10)) * OCH;
#pragma unroll
  for (int nt = 0; nt < 8; ++nt) {
    const int tb = t0 + wn * 128 + nt * 16 + quad * 4;
#pragma unroll
    for (int r = 0; r < 4; ++r) {
      const int t = tb + r;
      if (t < TY) {
#pragma unroll
        for (int mt = 0; mt < 4; ++mt) {
          const int o = o0 + wm * 64 + mt * 16 + col;
          yb[(size_t)t * OCH + o] = (_Float16)acc[mt][nt][r];
        }
      }
    }
  }
}

// ---------------------------------------------------------------------------
// Kernel 3: adaptive avg pool (overlapping torch bins) + bias, half8 wide.
// out[b][w][o] = bias[o] + mean_{t in bin(w)} y[b][t][o]
// one (b, w, o-octet) per thread: 32*128*64 = 262144 = 1024 blocks x 256.
// ---------------------------------------------------------------------------
__global__ __launch_bounds__(256) void pool_kernel(const _Float16* __restrict__ y,
                                                   const float* __restrict__ bias,
                                                   float* __restrict__ out) {
  const int unit = blockIdx.x * 256 + threadIdx.x;
  const int b = unit >> 13;
  const int w = (unit >> 6) & 127;
  const int o = (unit & 63) * 8;
  const int start = (w * TY) >> 7;
  const int end = ((w + 1) * TY + 127) >> 7;
  const _Float16* yb = y + (((size_t)b << 10)) * OCH;
  float s[8];
#pragma unroll
  for (int i = 0; i < 8; ++i) s[i] = 0.0f;
  for (int t = start; t < end; ++t) {
    half8 v = *(const half8*)(yb + (size_t)t * OCH + o);
#pragma unroll
    for (int i = 0; i < 8; ++i) s[i] += (float)v[i];
  }
  const float inv = 1.0f / (float)(end - start);
  float* op = out + ((size_t)b * OUTW + w) * OCH + o;
  floatx4 r0, r1;
#pragma unroll
  for (int i = 0; i < 4; ++i) r0[i] = s[i] * inv + bias[o + i];
#pragma unroll
  for (int i = 0; i < 4; ++i) r1[i] = s[4 + i] * inv + bias[o + 4 + i];
  *(floatx4*)(op) = r0;
  *(floatx4*)(op + 4) = r1;
}

// ---------------------------------------------------------------------------
extern "C" void kernel_launch(void* const* d_in, const int* in_sizes, int n_in,
                              void* d_out, int out_size, void* d_ws, size_t ws_size,
                              hipStream_t stream) {
  const float* x = (const float*)d_in[0];       // [32, 4096, 64]
  const float* weight = (const float*)d_in[1];  // [512, 576, 3]
  const float* bias = (const float*)d_in[2];    // [512]
  float* out = (float*)d_out;                   // [32, 128, 512]

  char* ws = (char*)d_ws;
  const size_t m_bytes = (size_t)BATCH * T_ROWS * ICH * sizeof(_Float16);  // 38,043,648
  const size_t w_bytes = (size_t)3 * OCH * ICH * sizeof(_Float16);         // 1,769,472
  _Float16* m_ws = (_Float16*)ws;
  _Float16* wk = (_Float16*)(ws + m_bytes);
  _Float16* y = (_Float16*)(ws + m_bytes + w_bytes);  // [32][1024][512] fp16

  hipLaunchKernelGGL(stft_wrepack_kernel, dim3(258, BATCH), dim3(256), 0,
                     stream, x, weight, m_ws, wk);
  hipLaunchKernelGGL(conv_gemm_kernel, dim3(512), dim3(256), 0, stream,
                     m_ws, wk, y);
  hipLaunchKernelGGL(pool_kernel, dim3(OUTW * BATCH / 4), dim3(256), 0, stream,
                     y, bias, out);
}